// Round 5
// baseline (534.147 us; speedup 1.0000x reference)
//
#include <hip/hip_runtime.h>
#include <cstdint>

// ---------------------------------------------------------------------------
// GCNRecommender round 5 (= round 4 with the compile fix):
//  - agg: 16 lanes/edge x 4 slots/wave, 8 rows in flight (4x MLP vs round 3)
//  - L1 GEMM stages fp32 A directly (f2bf fused into LDS staging)
//  - wave-per-row LN for F=64
//  - CSR build, bf16 MFMA GEMMs otherwise unchanged
// ---------------------------------------------------------------------------

#define LN_EPS 1e-5f

typedef __attribute__((ext_vector_type(8))) short bf16x8;
typedef __attribute__((ext_vector_type(4))) float f32x4;

static __device__ __forceinline__ ushort f2bf(float f) {
  union { float f; uint u; } c; c.f = f;
  uint u = c.u;
  return (ushort)((u + 0x7fffu + ((u >> 16) & 1u)) >> 16);  // RNE
}
static __device__ __forceinline__ float bf2f(ushort h) {
  union { uint u; float f; } c; c.u = (uint)h << 16;
  return c.f;
}
static __device__ __forceinline__ float bflo(uint u) {
  union { uint u; float f; } c; c.u = u << 16;
  return c.f;
}
static __device__ __forceinline__ float bfhi(uint u) {
  union { uint u; float f; } c; c.u = u & 0xffff0000u;
  return c.f;
}

// ---------------- CSR build ----------------

__global__ void zero1_kernel(int* __restrict__ a, int n) {
  int i = blockIdx.x * blockDim.x + threadIdx.x;
  if (i < n) a[i] = 0;
}

__global__ void deg_kernel(const int* __restrict__ dst, int* __restrict__ deg, int E) {
  int e = blockIdx.x * blockDim.x + threadIdx.x;
  if (e < E) atomicAdd(&deg[dst[e]], 1);
}

__global__ void scan1_kernel(const int* __restrict__ deg, int* __restrict__ excl,
                             int* __restrict__ bsums, float* __restrict__ dinv, int N) {
  __shared__ int s[256];
  int tid = threadIdx.x;
  int i = blockIdx.x * 256 + tid;
  int v = (i < N) ? deg[i] : 0;
  s[tid] = v;
  __syncthreads();
  for (int o = 1; o < 256; o <<= 1) {
    int t = (tid >= o) ? s[tid - o] : 0;
    __syncthreads();
    if (tid >= o) s[tid] += t;
    __syncthreads();
  }
  if (i < N) {
    excl[i] = s[tid] - v;
    dinv[i] = rsqrtf((float)v + 1.0f);  // +1 self-loop
  }
  if (tid == 255) bsums[blockIdx.x] = s[tid];
}

__global__ void scan2_kernel(int* __restrict__ bsums, int nb) {
  __shared__ int s[256];
  int tid = threadIdx.x;
  int v = (tid < nb) ? bsums[tid] : 0;
  s[tid] = v;
  __syncthreads();
  for (int o = 1; o < 256; o <<= 1) {
    int t = (tid >= o) ? s[tid - o] : 0;
    __syncthreads();
    if (tid >= o) s[tid] += t;
    __syncthreads();
  }
  if (tid < nb) bsums[tid] = s[tid] - v;
}

__global__ void scan3_kernel(int* __restrict__ rowptr, int* __restrict__ fill,
                             const int* __restrict__ bsums, int N, int Etotal) {
  int i = blockIdx.x * blockDim.x + threadIdx.x;
  if (i < N) {
    int v = rowptr[i] + bsums[i >> 8];
    rowptr[i] = v;
    fill[i] = v;
  } else if (i == N) {
    rowptr[N] = Etotal;
  }
}

__global__ void fill_kernel(const int* __restrict__ src, const int* __restrict__ dst,
                            int* __restrict__ fill, int* __restrict__ srcs, int E) {
  int e = blockIdx.x * blockDim.x + threadIdx.x;
  if (e >= E) return;
  int idx = atomicAdd(&fill[dst[e]], 1);
  srcs[idx] = src[e];
}

// ---------------- weight conversion ----------------

struct WConvArgs {
  const float* w[5];
  ushort* wt[5];
  int K[5], N[5];
  int off[6];
};

// W[K][N] fp32 -> Wt[N][K] bf16
__global__ void wconv_kernel(WConvArgs a, int total) {
  int i = blockIdx.x * blockDim.x + threadIdx.x;
  if (i >= total) return;
  int m = 0;
  while (i >= a.off[m + 1]) m++;
  int j = i - a.off[m];
  int k = j / a.N[m], n = j - k * a.N[m];
  a.wt[m][(size_t)n * a.K[m] + k] = f2bf(a.w[m][j]);
}

// ---------------- bf16 MFMA GEMM ----------------
// C[M][N] = A[M][K] @ Bt[N][K]^T (+ bias). K % 32 == 0.
#define TBM 128
#define TBN 128
#define TBK 32
#define LDK 40

template <bool A_FP32, bool OUT_BF16>
__global__ __launch_bounds__(256, 2) void mfma_gemm_kernel(
    const void* __restrict__ Ain, const ushort* __restrict__ Bt,
    const float* __restrict__ bias, void* __restrict__ Cout,
    int M, int N, int K) {
  __shared__ ushort As[TBM][LDK];
  __shared__ ushort Bs[TBN][LDK];
  const int tid = threadIdx.x;
  const int lane = tid & 63;
  const int w = tid >> 6;
  const int wm = w & 1, wn = w >> 1;
  const int quad = lane >> 4, l16 = lane & 15;
  const int rowBase = blockIdx.y * TBM;
  const int colBase = blockIdx.x * TBN;

  f32x4 acc[4][4] = {};
  const int sr = tid >> 1;        // 0..127 staging row
  const int sk = (tid & 1) * 16;  // k offset 0 / 16

  for (int k0 = 0; k0 < K; k0 += TBK) {
    // ---- stage A ----
    {
      int grow = rowBase + sr;
      if (A_FP32) {
        const float* Af = (const float*)Ain;
        float4 f0 = {}, f1 = {}, f2 = {}, f3 = {};
        if (grow < M) {
          const float4* ap = (const float4*)(Af + (size_t)grow * K + k0 + sk);
          f0 = ap[0]; f1 = ap[1]; f2 = ap[2]; f3 = ap[3];
        }
        ushort t[16] = {f2bf(f0.x), f2bf(f0.y), f2bf(f0.z), f2bf(f0.w),
                        f2bf(f1.x), f2bf(f1.y), f2bf(f1.z), f2bf(f1.w),
                        f2bf(f2.x), f2bf(f2.y), f2bf(f2.z), f2bf(f2.w),
                        f2bf(f3.x), f2bf(f3.y), f2bf(f3.z), f2bf(f3.w)};
        *(uint4*)&As[sr][sk] = *(const uint4*)&t[0];
        *(uint4*)&As[sr][sk + 8] = *(const uint4*)&t[8];
      } else {
        const ushort* Ab = (const ushort*)Ain;
        uint4 v0 = {}, v1 = {};
        if (grow < M) {
          const uint4* ap = (const uint4*)(Ab + (size_t)grow * K + k0 + sk);
          v0 = ap[0]; v1 = ap[1];
        }
        *(uint4*)&As[sr][sk] = v0;
        *(uint4*)&As[sr][sk + 8] = v1;
      }
    }
    // ---- stage B ----
    {
      int gcol = colBase + sr;
      uint4 v0 = {}, v1 = {};
      if (gcol < N) {
        const uint4* bp = (const uint4*)(Bt + (size_t)gcol * K + k0 + sk);
        v0 = bp[0]; v1 = bp[1];
      }
      *(uint4*)&Bs[sr][sk] = v0;
      *(uint4*)&Bs[sr][sk + 8] = v1;
    }
    __syncthreads();
    bf16x8 af[4], bfr[4];
#pragma unroll
    for (int i = 0; i < 4; i++) {
      af[i]  = *(const bf16x8*)&As[wm * 64 + i * 16 + l16][quad * 8];
      bfr[i] = *(const bf16x8*)&Bs[wn * 64 + i * 16 + l16][quad * 8];
    }
#pragma unroll
    for (int i = 0; i < 4; i++)
#pragma unroll
      for (int j = 0; j < 4; j++)
        acc[i][j] = __builtin_amdgcn_mfma_f32_16x16x32_bf16(af[i], bfr[j], acc[i][j], 0, 0, 0);
    __syncthreads();
  }
#pragma unroll
  for (int i = 0; i < 4; i++) {
    int row0 = rowBase + wm * 64 + i * 16 + quad * 4;
#pragma unroll
    for (int j = 0; j < 4; j++) {
      int col = colBase + wn * 64 + j * 16 + l16;
      if (col >= N) continue;
      float bv = bias ? bias[col] : 0.f;
#pragma unroll
      for (int r = 0; r < 4; r++) {
        int row = row0 + r;
        if (row >= M) continue;
        float v = acc[i][j][r] + bv;
        if (OUT_BF16) ((ushort*)Cout)[(size_t)row * N + col] = f2bf(v);
        else          ((float*)Cout)[(size_t)row * N + col] = v;
      }
    }
  }
}

// ---------------- aggregation, F=128 bf16 ----------------
// 16 lanes per edge-slot, 4 slots per wave, 8 edges in flight per iteration.
// Lane sl (0..15) covers features [8sl..8sl+7] via one uint4 (16 B) per row.
// coef = dinv[src]*dinv[n] computed on the fly.
template <bool DO_LN>
__global__ __launch_bounds__(256) void agg_kernel(
    const ushort* __restrict__ hb, const int* __restrict__ rowptr,
    const int* __restrict__ srcs, const float* __restrict__ dinv,
    const float* __restrict__ bias, const float* __restrict__ g,
    const float* __restrict__ be, uint* __restrict__ out, int Nn) {
  const int wave = threadIdx.x >> 6;
  const int n = blockIdx.x * 4 + wave;
  if (n >= Nn) return;
  const int lane = threadIdx.x & 63;
  const int slot = lane >> 4;
  const int sl = lane & 15;
  const float di = dinv[n];

  float acc[8] = {};
  {  // self-loop term (counted once: slot 0 only)
    uint4 v = ((const uint4*)(hb + (size_t)n * 128))[sl];
    float c = (slot == 0) ? di * di : 0.f;
    acc[0] = c * bflo(v.x); acc[1] = c * bfhi(v.x);
    acc[2] = c * bflo(v.y); acc[3] = c * bfhi(v.y);
    acc[4] = c * bflo(v.z); acc[5] = c * bfhi(v.z);
    acc[6] = c * bflo(v.w); acc[7] = c * bfhi(v.w);
  }
  const int e0 = rowptr[n], e1 = rowptr[n + 1];
  for (int i = e0; i < e1; i += 8) {
    int i0 = i + slot, i1 = i + 4 + slot;
    int s0 = (i0 < e1) ? srcs[i0] : 0;
    int s1 = (i1 < e1) ? srcs[i1] : 0;
    float c0 = (i0 < e1) ? dinv[s0] * di : 0.f;
    float c1 = (i1 < e1) ? dinv[s1] * di : 0.f;
    uint4 v0 = ((const uint4*)(hb + (size_t)s0 * 128))[sl];
    uint4 v1 = ((const uint4*)(hb + (size_t)s1 * 128))[sl];
    acc[0] += c0 * bflo(v0.x) + c1 * bflo(v1.x);
    acc[1] += c0 * bfhi(v0.x) + c1 * bfhi(v1.x);
    acc[2] += c0 * bflo(v0.y) + c1 * bflo(v1.y);
    acc[3] += c0 * bfhi(v0.y) + c1 * bfhi(v1.y);
    acc[4] += c0 * bflo(v0.z) + c1 * bflo(v1.z);
    acc[5] += c0 * bfhi(v0.z) + c1 * bfhi(v1.z);
    acc[6] += c0 * bflo(v0.w) + c1 * bflo(v1.w);
    acc[7] += c0 * bfhi(v0.w) + c1 * bfhi(v1.w);
  }
  // combine the 4 slots (lanes with equal sl hold the same features)
#pragma unroll
  for (int j = 0; j < 8; j++) {
    acc[j] += __shfl_xor(acc[j], 16);
    acc[j] += __shfl_xor(acc[j], 32);
  }
  if (DO_LN) {
    float4 bv0 = ((const float4*)bias)[2 * sl];
    float4 bv1 = ((const float4*)bias)[2 * sl + 1];
    acc[0] += bv0.x; acc[1] += bv0.y; acc[2] += bv0.z; acc[3] += bv0.w;
    acc[4] += bv1.x; acc[5] += bv1.y; acc[6] += bv1.z; acc[7] += bv1.w;
    float s = acc[0] + acc[1] + acc[2] + acc[3] + acc[4] + acc[5] + acc[6] + acc[7];
#pragma unroll
    for (int o = 1; o <= 8; o <<= 1) s += __shfl_xor(s, o);
    float mean = s * (1.0f / 128.0f);
    float q = 0.f;
#pragma unroll
    for (int j = 0; j < 8; j++) {
      acc[j] -= mean;
      q += acc[j] * acc[j];
    }
#pragma unroll
    for (int o = 1; o <= 8; o <<= 1) q += __shfl_xor(q, o);
    float rstd = rsqrtf(q * (1.0f / 128.0f) + LN_EPS);
    float4 gv0 = ((const float4*)g)[2 * sl];
    float4 gv1 = ((const float4*)g)[2 * sl + 1];
    float4 ev0 = ((const float4*)be)[2 * sl];
    float4 ev1 = ((const float4*)be)[2 * sl + 1];
    float gg[8] = {gv0.x, gv0.y, gv0.z, gv0.w, gv1.x, gv1.y, gv1.z, gv1.w};
    float ee[8] = {ev0.x, ev0.y, ev0.z, ev0.w, ev1.x, ev1.y, ev1.z, ev1.w};
#pragma unroll
    for (int j = 0; j < 8; j++) {
      float y = acc[j] * rstd * gg[j] + ee[j];
      acc[j] = (y > 0.f) ? y : expm1f(y);
    }
  }
  if (slot == 0) {
    uint4 o;
    o.x = (uint)f2bf(acc[0]) | ((uint)f2bf(acc[1]) << 16);
    o.y = (uint)f2bf(acc[2]) | ((uint)f2bf(acc[3]) << 16);
    o.z = (uint)f2bf(acc[4]) | ((uint)f2bf(acc[5]) << 16);
    o.w = (uint)f2bf(acc[6]) | ((uint)f2bf(acc[7]) << 16);
    ((uint4*)(out + (size_t)n * 64))[sl] = o;
  }
}

// ---------------- LayerNorm + ELU ----------------

// F=256, one block (256 thr) per row, bf16 in -> bf16 out
__global__ __launch_bounds__(256) void ln_elu256_kernel(const ushort* __restrict__ xin,
                                                        const float* __restrict__ g,
                                                        const float* __restrict__ be,
                                                        ushort* __restrict__ out) {
  __shared__ float sb[4];
  const int row = blockIdx.x;
  const int f = threadIdx.x;
  float v = bf2f(xin[(size_t)row * 256 + f]);
  float s = v;
#pragma unroll
  for (int o = 32; o >= 1; o >>= 1) s += __shfl_xor(s, o);
  if ((f & 63) == 0) sb[f >> 6] = s;
  __syncthreads();
  float mean = (sb[0] + sb[1] + sb[2] + sb[3]) * (1.0f / 256.0f);
  __syncthreads();
  float d = v - mean;
  float q = d * d;
#pragma unroll
  for (int o = 32; o >= 1; o >>= 1) q += __shfl_xor(q, o);
  if ((f & 63) == 0) sb[f >> 6] = q;
  __syncthreads();
  float var = (sb[0] + sb[1] + sb[2] + sb[3]) * (1.0f / 256.0f);
  float y = d * rsqrtf(var + LN_EPS) * g[f] + be[f];
  out[(size_t)row * 256 + f] = f2bf((y > 0.f) ? y : expm1f(y));
}

// F=64, one wave per row, fp32 in -> bf16 out
__global__ __launch_bounds__(256) void ln_elu64_kernel(const float* __restrict__ xin,
                                                       const float* __restrict__ g,
                                                       const float* __restrict__ be,
                                                       ushort* __restrict__ out, int Nn) {
  const int n = blockIdx.x * 4 + (threadIdx.x >> 6);
  if (n >= Nn) return;
  const int f = threadIdx.x & 63;
  float v = xin[(size_t)n * 64 + f];
  float s = v;
#pragma unroll
  for (int o = 32; o >= 1; o >>= 1) s += __shfl_xor(s, o);
  float mean = s * (1.0f / 64.0f);
  float d = v - mean;
  float q = d * d;
#pragma unroll
  for (int o = 32; o >= 1; o >>= 1) q += __shfl_xor(q, o);
  float y = d * rsqrtf(q * (1.0f / 64.0f) + LN_EPS) * g[f] + be[f];
  out[(size_t)n * 64 + f] = f2bf((y > 0.f) ? y : expm1f(y));
}

// ---------------- host ----------------

extern "C" void kernel_launch(void* const* d_in, const int* in_sizes, int n_in,
                              void* d_out, int out_size, void* d_ws, size_t ws_size,
                              hipStream_t stream) {
  const float* x   = (const float*)d_in[0];
  const int*   ei  = (const int*)d_in[1];
  const float* W1  = (const float*)d_in[2];
  const float* b1  = (const float*)d_in[3];
  const float* g1  = (const float*)d_in[4];
  const float* be1 = (const float*)d_in[5];
  const float* W2  = (const float*)d_in[6];
  const float* b2  = (const float*)d_in[7];
  const float* g2  = (const float*)d_in[8];
  const float* be2 = (const float*)d_in[9];
  const float* W3  = (const float*)d_in[10];
  const float* b3  = (const float*)d_in[11];
  const float* g3  = (const float*)d_in[12];
  const float* be3 = (const float*)d_in[13];
  const float* Wl1 = (const float*)d_in[14];
  const float* bl1 = (const float*)d_in[15];
  const float* g4  = (const float*)d_in[16];
  const float* be4 = (const float*)d_in[17];
  const float* Wl2 = (const float*)d_in[18];
  const float* bl2 = (const float*)d_in[19];

  const int N = in_sizes[0] / 128;  // 50000
  const int E = in_sizes[1] / 2;    // 800000
  const int* esrc = ei;
  const int* edst = ei + E;

  // workspace layout
  char* p = (char*)d_ws;
  float* F1 = (float*)p;              p += (size_t)N * 128 * 4;  // fp32 scratch (L4)
  ushort* Pb = (ushort*)p;            p += (size_t)N * 256 * 2;  // bf16 act buf
  ushort* Qb = (ushort*)p;            p += (size_t)N * 256 * 2;
  ushort* W1t = (ushort*)p;           p += 128 * 128 * 2;
  ushort* W2t = (ushort*)p;           p += 128 * 256 * 2;
  ushort* W3t = (ushort*)p;           p += 256 * 128 * 2;
  ushort* Wl1t = (ushort*)p;          p += 128 * 64 * 2;
  ushort* Wl2t = (ushort*)p;          p += 64 * 500 * 2;
  int*   srcs  = (int*)p;             p += (size_t)E * 4;
  int*   deg   = (int*)p;             p += (size_t)N * 4;
  float* dinv  = (float*)p;           p += (size_t)N * 4;
  int*   rowptr= (int*)p;             p += (size_t)(N + 2) * 4;
  int*   fill  = (int*)p;             p += (size_t)N * 4;
  int*   bsums = (int*)p;             p += 256 * 4;

  const int nb = (N + 255) / 256;
  const int eb = (E + 255) / 256;

  // ---- CSR build ----
  zero1_kernel<<<nb, 256, 0, stream>>>(deg, N);
  deg_kernel<<<eb, 256, 0, stream>>>(edst, deg, E);
  scan1_kernel<<<nb, 256, 0, stream>>>(deg, rowptr, bsums, dinv, N);
  scan2_kernel<<<1, 256, 0, stream>>>(bsums, nb);
  scan3_kernel<<<(N + 256) / 256, 256, 0, stream>>>(rowptr, fill, bsums, N, E);
  fill_kernel<<<eb, 256, 0, stream>>>(esrc, edst, fill, srcs, E);

  // ---- weight conversion ----
  WConvArgs wa;
  wa.w[0] = W1;  wa.wt[0] = W1t;  wa.K[0] = 128; wa.N[0] = 128;
  wa.w[1] = W2;  wa.wt[1] = W2t;  wa.K[1] = 128; wa.N[1] = 256;
  wa.w[2] = W3;  wa.wt[2] = W3t;  wa.K[2] = 256; wa.N[2] = 128;
  wa.w[3] = Wl1; wa.wt[3] = Wl1t; wa.K[3] = 128; wa.N[3] = 64;
  wa.w[4] = Wl2; wa.wt[4] = Wl2t; wa.K[4] = 64;  wa.N[4] = 500;
  wa.off[0] = 0;
  for (int m = 0; m < 5; m++) wa.off[m + 1] = wa.off[m] + wa.K[m] * wa.N[m];
  int wtotal = wa.off[5];
  wconv_kernel<<<(wtotal + 255) / 256, 256, 0, stream>>>(wa, wtotal);

  const int ab = (N + 3) / 4;

  // L1: h1 = elu(LN(Agg(x@W1) + b1))
  {
    dim3 grid((128 + TBN - 1) / TBN, (N + TBM - 1) / TBM);
    mfma_gemm_kernel<true, true><<<grid, 256, 0, stream>>>(x, W1t, nullptr, Pb, N, 128, 128);
  }
  agg_kernel<true><<<ab, 256, 0, stream>>>(Pb, rowptr, srcs, dinv, b1, g1, be1, (uint*)Qb, N);

  // L2: h2 = elu(LN(Agg(h1)@W2 + b2))
  agg_kernel<false><<<ab, 256, 0, stream>>>(Qb, rowptr, srcs, dinv, nullptr, nullptr, nullptr, (uint*)Pb, N);
  {
    dim3 grid((256 + TBN - 1) / TBN, (N + TBM - 1) / TBM);
    mfma_gemm_kernel<false, true><<<grid, 256, 0, stream>>>(Pb, W2t, b2, Qb, N, 256, 128);
  }
  ln_elu256_kernel<<<N, 256, 0, stream>>>(Qb, g2, be2, Pb);

  // L3: h3 = elu(LN(Agg(h2@W3) + b3))
  {
    dim3 grid((128 + TBN - 1) / TBN, (N + TBM - 1) / TBM);
    mfma_gemm_kernel<false, true><<<grid, 256, 0, stream>>>(Pb, W3t, nullptr, Qb, N, 128, 256);
  }
  agg_kernel<true><<<ab, 256, 0, stream>>>(Qb, rowptr, srcs, dinv, b3, g3, be3, (uint*)Pb, N);

  // L4: h4 = elu(LN(h3@Wl1 + bl1))
  {
    dim3 grid((64 + TBN - 1) / TBN, (N + TBM - 1) / TBM);
    mfma_gemm_kernel<false, false><<<grid, 256, 0, stream>>>(Pb, Wl1t, bl1, F1, N, 64, 128);
  }
  ln_elu64_kernel<<<ab, 256, 0, stream>>>(F1, g4, be4, Qb, N);

  // L5: out = h4@Wl2 + bl2
  {
    dim3 grid((500 + TBN - 1) / TBN, (N + TBM - 1) / TBM);
    mfma_gemm_kernel<false, false><<<grid, 256, 0, stream>>>(Qb, Wl2t, bl2, d_out, N, 500, 64);
  }
}